// Round 11
// baseline (172.109 us; speedup 1.0000x reference)
//
#include <hip/hip_runtime.h>

typedef __attribute__((ext_vector_type(8))) short short8;    // 8 bf16 (MFMA A/B frag)
typedef __attribute__((ext_vector_type(4))) float floatx4;   // 16x16 MFMA C/D frag
typedef __attribute__((ext_vector_type(16))) float floatx16; // 32x32 MFMA C/D frag

// Per-wave LDS staging: 100 halo pixels x 12 dwords (bf16x2[8] = 16ch | pad).
// pitch 12 dwords = 48B = 3 x 16B slots: stride 3 coprime with 8 bank-groups.
// K4 (R11): TWO buffers per wave (A/B) so edge i+1 staging is independent of
// edge i ds_reads -> compiler interleaves staging VALU with MFMA.
#define PITCH 12
#define REGSZ 1200
#define CAP 64            // fixed bucket capacity per node (mean deg = 6)
#define LOG2E 1.44269504088896340736f
#define LN2   0.6931471805599453f

__device__ __forceinline__ float frcp(float x) { return __builtin_amdgcn_rcpf(x); }
__device__ __forceinline__ float fsoftplus(float x) {
    return fmaxf(x, 0.f) + __logf(1.f + __expf(-fabsf(x)));
}
__device__ __forceinline__ float felu(float x) { return x > 0.f ? x : __expf(x) - 1.f; }

// RNE fp32 pair -> packed bf16x2 (a0 in low half, a1 in high half)
__device__ __forceinline__ unsigned pack2_rne(float a0, float a1) {
    unsigned u0 = __float_as_uint(a0), u1 = __float_as_uint(a1);
    u0 += 0x7fff + ((u0 >> 16) & 1);
    u1 += 0x7fff + ((u1 >> 16) & 1);
    return __builtin_amdgcn_perm(u1, u0, 0x07060302);  // [u1.b3,u1.b2,u0.b3,u0.b2]
}
__device__ __forceinline__ unsigned short f2bf_rne(float x) {
    unsigned u = __float_as_uint(x);
    u += 0x7fff + ((u >> 16) & 1);
    return (unsigned short)(u >> 16);
}
__device__ __forceinline__ float bf2f(unsigned short h) {
    return __uint_as_float(((unsigned)h) << 16);
}
// unpack packed bf16x2 word -> two floats (low = even channel)
__device__ __forceinline__ float up_lo(unsigned u) { return __uint_as_float(u << 16); }
__device__ __forceinline__ float up_hi(unsigned u) { return __uint_as_float(u & 0xffff0000u); }

// ---------------------------------------------------------------------------
// K1: fused histogram+scatter (blocks 0..nhist-1) + prep (8 blocks).
// Scan-free: fixed-capacity buckets (CAP slots/node); one atomic pass yields
// degree (counts) + grouped targets (bucket_tgt). Prep parallelized over 8
// blocks. wfrag_lin (10240): 16x16x32 B-operand layout for K4 (log2e-scaled;
// K4 reads only the hi half); wfrag_node (9216): 32x32x16 A-operand layout
// for K3 (K3 reads only ver=0/hi; lo kept for possible revert).
// ---------------------------------------------------------------------------
__global__ __launch_bounds__(256) void prep_scatter_kernel(
    const float* __restrict__ edge_w, const float* __restrict__ node_w,
    const float* __restrict__ lin_w, const int* __restrict__ esrc,
    const int* __restrict__ etgt,
    short* __restrict__ wfrag_lin, short* __restrict__ wfrag_node,
    int* __restrict__ counts, int* __restrict__ bucket_tgt, int E, int nhist)
{
    const int t = threadIdx.x;
    if ((int)blockIdx.x < nhist) {
        int i = blockIdx.x * 256 + t;
        if (i < E) {
            int s = esrc[i];
            int pos = atomicAdd(&counts[s], 1);
            if (pos < CAP) bucket_tgt[s * CAP + pos] = etgt[i];
        }
        return;
    }
    const int pb = blockIdx.x - nhist;   // 0..7
    // lin fragments: 16x16x32 B-operand (ver x nt x s x lane x j), log2e-scaled
    for (int i = pb * 256 + t; i < 10240; i += 2048) {
        int idx = i;
        int j = idx & 7; idx >>= 3;
        int lane = idx & 63; idx >>= 6;
        int s = idx % 5; idx /= 5;
        int nt = idx & 1;
        int ver = idx >> 1;
        int q = lane >> 4;
        int tap = 2 * s + (q >> 1);
        int cin = (q & 1) * 8 + j;
        int cout = nt * 16 + (lane & 15);
        float v = (tap < 9) ? lin_w[cout * 144 + cin * 9 + tap] * LOG2E : 0.f;
        unsigned short hi = f2bf_rne(v);
        wfrag_lin[i] = (short)(ver ? f2bf_rne(v - bf2f(hi)) : hi);
    }
    // node fragments: 32x32x16 A-operand (ver x tap x lane x j)
    for (int i = pb * 256 + t; i < 9216; i += 2048) {
        int j = i & 7;
        int lane = (i >> 3) & 63;
        int rest = i >> 9;            // 0..17
        int tap = rest % 9;
        int ver = rest / 9;           // 0=hi, 1=lo
        int row = lane & 31;
        int cin = (lane >> 5) * 8 + j;
        const float* src = (row < 16) ? edge_w : node_w;
        float v = src[(row & 15) * 144 + cin * 9 + tap];
        unsigned short hi = f2bf_rne(v);
        wfrag_node[i] = (short)(ver ? f2bf_rne(v - bf2f(hi)) : hi);
    }
}

// ---------------------------------------------------------------------------
// K3: degree-descending node order (block 0 -- R11: moved from last block to
// FIRST so it overlaps the convs instead of running as a serial tail) +
// node convs via 32x32x16 MFMA (blocks 1..nconv, 4 nodes/block).
// W hi-only (R10): 18 MFMA/node. zc/nc output as packed bf16x2 (adjacent-
// channel pairs = adjacent acc regs; row m = (i&1)+4*(i>>1)+2q).
// Memory-bound (~65 MB traffic): R10's compute halving was time-neutral.
// launch_bounds(256,3): (x,4) caps at 64 arch VGPRs and SPILLS (R1).
// ---------------------------------------------------------------------------
__global__ __launch_bounds__(256, 3) void conv_order_kernel(
    const float* __restrict__ atom, const short* __restrict__ wfrag_node,
    unsigned* __restrict__ zcp, unsigned* __restrict__ ncp,
    const int* __restrict__ counts, int* __restrict__ nlist,
    int N, int nconv)
{
    __shared__ unsigned zbuf[4 * REGSZ];     // 19.2 KB (conv part only)
    __shared__ int bh[64], bo[64];           // order part
    const int t = threadIdx.x;
    const int b = blockIdx.x;

    if (b == 0) {
        // ----- order: counting sort of nodes by degree, DESCENDING -----
        if (t < 64) bh[t] = 0;
        __syncthreads();
        for (int n = t; n < N; n += 256) {
            int deg = min(counts[n], CAP);
            atomicAdd(&bh[min(deg, 63)], 1);
        }
        __syncthreads();
        if (t == 0) {
            int run = 0;
            for (int d = 63; d >= 0; --d) { bo[d] = run; run += bh[d]; }
        }
        __syncthreads();
        for (int n = t; n < N; n += 256) {
            int deg = min(counts[n], CAP);
            int pos = atomicAdd(&bo[min(deg, 63)], 1);
            nlist[pos] = n;
        }
        return;
    }

    // ----- conv: 1 wave = 1 node, no barriers -----
    const int lane = t & 63;
    const int wv = t >> 6;
    const int n = (b - 1) * 4 + wv;
    if (n >= N) return;
    unsigned* zb = &zbuf[wv * REGSZ];
    for (int i = lane; i < REGSZ; i += 64) zb[i] = 0u;

    const int q = lane >> 5;       // cin-half (A/B k-half), outch +4q in D
    const int pcol = lane & 31;    // D column = pixel within tile

    const short8* wf = (const short8*)wfrag_node;
    short8 W[9];                   // hi-only (ver=0)
    #pragma unroll
    for (int tap = 0; tap < 9; ++tap)
        W[tap] = wf[tap * 64 + lane];

    const size_t nb = (size_t)n * 1024;
    float a[16];
    #pragma unroll
    for (int k = 0; k < 16; ++k) a[k] = atom[nb + k * 64 + lane];
    unsigned h[8];
    #pragma unroll
    for (int d = 0; d < 8; ++d) h[d] = pack2_rne(a[2 * d], a[2 * d + 1]);
    const int sbase = (((lane >> 3) + 1) * 10 + (lane & 7) + 1) * PITCH;
    *(uint4*)&zb[sbase]     = make_uint4(h[0], h[1], h[2], h[3]);
    *(uint4*)&zb[sbase + 4] = make_uint4(h[4], h[5], h[6], h[7]);

    // read base for tile0 pixel (pcol); tile1 = +4 rows = +480 dwords.
    const int rbase = ((pcol >> 3) * 10 + (pcol & 7)) * PITCH + q * 4;
    const size_t nbp = (size_t)n * 512;      // packed bf16x2 node block

    #pragma unroll
    for (int t2 = 0; t2 < 2; ++t2) {
        floatx16 acc = {0.f, 0.f, 0.f, 0.f, 0.f, 0.f, 0.f, 0.f,
                        0.f, 0.f, 0.f, 0.f, 0.f, 0.f, 0.f, 0.f};
        #pragma unroll
        for (int ky = 0; ky < 3; ++ky)
            #pragma unroll
            for (int kx = 0; kx < 3; ++kx) {
                short8 B = *(const short8*)&zb[rbase + t2 * 480 + (ky * 10 + kx) * PITCH];
                acc = __builtin_amdgcn_mfma_f32_32x32x16_bf16(W[ky * 3 + kx], B, acc, 0, 0, 0);
            }
        const int p = t2 * 32 + pcol;
        // channel-pair rows: pair i covers ch (2m, 2m+1), m = (i&1)+4*(i>>1)+2q
        #pragma unroll
        for (int i = 0; i < 4; ++i) {
            int m = (i & 1) + 4 * (i >> 1) + 2 * q;
            zcp[nbp + (size_t)m * 64 + p] = pack2_rne(acc[2 * i], acc[2 * i + 1]);
            ncp[nbp + (size_t)m * 64 + p] = pack2_rne(acc[8 + 2 * i], acc[9 + 2 * i]);
        }
    }
}

// ---------------------------------------------------------------------------
// K4: node-major edge processing; 1 wave = 1 node (degree-sorted via nlist).
// R11: DOUBLE-BUFFERED LDS staging. Previously edge i+1's ds_write hit the
// same addresses as edge i's ds_reads -> fully serial chain
// (zvp->felu->pack->write->read->MFMA->trans). With bufA/bufB alternating
// (odd-peel + branchless pair-unrolled loop, prefetch indices clamped to
// deg-1), edge i+1 staging is independent of edge i MFMAs -> scheduler
// interleaves. Pure scheduling change: absmax must stay bit-identical.
// 16x16x32 8-chain MFMA (R4-proven), W hi-only (R9), packed zc/nc (R8),
// wave-uniform readfirstlane (R9), exp2-domain epilogue.
// launch_bounds(128,3): no spill ((x,4) caps at 64 arch VGPRs and spills).
// ---------------------------------------------------------------------------
__global__ __launch_bounds__(128, 3) void node_edge_kernel(
    const float* __restrict__ atom, const unsigned* __restrict__ zcp,
    const unsigned* __restrict__ ncp, const int* __restrict__ counts,
    const int* __restrict__ bucket_tgt, const int* __restrict__ nlist,
    const short* __restrict__ wfrag_lin, const float* __restrict__ lin_b,
    const float* __restrict__ gamma, const float* __restrict__ beta,
    float* __restrict__ out, int N)
{
    __shared__ unsigned zbuf[4 * REGSZ];     // 2 waves x 2 buffers = 19.2 KB
    const int t = threadIdx.x;
    const int lane = t & 63;
    const int wv = t >> 6;
    const int ni = blockIdx.x * 2 + wv;
    if (ni >= N) return;
    const int n = __builtin_amdgcn_readfirstlane(nlist[ni]);
    const int c = lane & 15;
    const int q = lane >> 4;
    unsigned* zbA = &zbuf[wv * 2 * REGSZ];
    unsigned* zbB = zbA + REGSZ;
    for (int i = lane; i < 2 * REGSZ; i += 64) zbA[i] = 0u;

    const short8* wf = (const short8*)wfrag_lin;
    short8 W[2][5];                          // hi-only: [nt][s]
    #pragma unroll
    for (int nt = 0; nt < 2; ++nt)
        #pragma unroll
        for (int s = 0; s < 5; ++s)
            W[nt][s] = wf[(nt * 5 + s) * 64 + lane];

    int aoff[5];
    #pragma unroll
    for (int s = 0; s < 5; ++s) {
        int tap = 2 * s + (q >> 1);
        int ky = tap / 3, kx = tap - 3 * ky;
        aoff[s] = (tap < 9) ? ((((c >> 3) + ky) * 10 + (c & 7) + kx) * PITCH + (q & 1) * 4) : 0;
    }

    const size_t nb = (size_t)n * 1024;
    const size_t nbp = (size_t)n * 512;
    // nv: unpack packed nc once per node
    float nv[16];
    #pragma unroll
    for (int j = 0; j < 8; ++j) {
        unsigned u = ncp[nbp + (size_t)j * 64 + lane];
        nv[2 * j]     = up_lo(u);
        nv[2 * j + 1] = up_hi(u);
    }
    const int sbase = (((lane >> 3) + 1) * 10 + (lane & 7) + 1) * PITCH;

    const int off = n * CAP;
    const int deg = min(__builtin_amdgcn_readfirstlane(counts[n]), CAP);

    // exp2-domain biases (weights already carry the log2e factor)
    const float bf = lin_b[c] * LOG2E;
    const float bc = lin_b[c + 16] * LOG2E;
    float macc[4][4] = {{0.f}};

    if (deg > 0) {
        const int degm1 = deg - 1;
        unsigned zvp[8];
        {
            const unsigned* zp = zcp + (size_t)__builtin_amdgcn_readfirstlane(bucket_tgt[off]) * 512;
            #pragma unroll
            for (int j = 0; j < 8; ++j) zvp[j] = zp[(size_t)j * 64 + lane];
        }
        int tnext = __builtin_amdgcn_readfirstlane(bucket_tgt[off + min(1, degm1)]);

// one edge: consume zvp -> stage into ZB -> prefetch next zvp -> MFMA -> trans
#define EDGE_STEP(ZB, IT)                                                      \
    {                                                                          \
        float a_[16];                                                          \
        _Pragma("unroll")                                                      \
        for (int d = 0; d < 8; ++d) {                                          \
            float z0 = up_lo(zvp[d]), z1 = up_hi(zvp[d]);                      \
            a_[2 * d]     = felu(nv[2 * d] * z0);                              \
            a_[2 * d + 1] = felu(nv[2 * d + 1] * z1);                          \
        }                                                                      \
        {                                                                      \
            const unsigned* zp_ = zcp + (size_t)tnext * 512;                   \
            _Pragma("unroll")                                                  \
            for (int j = 0; j < 8; ++j) zvp[j] = zp_[(size_t)j * 64 + lane];   \
            tnext = __builtin_amdgcn_readfirstlane(                            \
                bucket_tgt[off + min((IT) + 2, degm1)]);                       \
        }                                                                      \
        unsigned h_[8];                                                        \
        _Pragma("unroll")                                                      \
        for (int d = 0; d < 8; ++d) h_[d] = pack2_rne(a_[2 * d], a_[2 * d + 1]); \
        *(uint4*)&(ZB)[sbase]     = make_uint4(h_[0], h_[1], h_[2], h_[3]);    \
        *(uint4*)&(ZB)[sbase + 4] = make_uint4(h_[4], h_[5], h_[6], h_[7]);    \
        _Pragma("unroll")                                                      \
        for (int mt = 0; mt < 4; ++mt) {                                       \
            floatx4 a0 = {bf, bf, bf, bf}, a1 = {bc, bc, bc, bc};              \
            const int mb = mt * 2 * 10 * PITCH;                                \
            _Pragma("unroll")                                                  \
            for (int s = 0; s < 5; ++s) {                                      \
                short8 Ah = *(const short8*)&(ZB)[mb + aoff[s]];               \
                a0 = __builtin_amdgcn_mfma_f32_16x16x32_bf16(Ah, W[0][s], a0, 0, 0, 0); \
                a1 = __builtin_amdgcn_mfma_f32_16x16x32_bf16(Ah, W[1][s], a1, 0, 0, 0); \
            }                                                                  \
            _Pragma("unroll")                                                  \
            for (int r = 0; r < 4; ++r) {                                      \
                float sg = frcp(1.f + __builtin_amdgcn_exp2f(-a0[r]));         \
                float e1 = __builtin_amdgcn_exp2f(-fabsf(a1[r]));              \
                float u = fmaxf(a1[r], 0.f) + __builtin_amdgcn_logf(1.f + e1); \
                macc[mt][r] = __builtin_fmaf(sg, u, macc[mt][r]);              \
            }                                                                  \
        }                                                                      \
    }

        int it = 0;
        if (deg & 1) {                       // odd peel -> bufA
            EDGE_STEP(zbA, 0);
            it = 1;
        }
        for (; it < deg; it += 2) {          // pairs: B then A, no inner branch
            EDGE_STEP(zbB, it);
            EDGE_STEP(zbA, it + 1);
        }
#undef EDGE_STEP
    }

    // fused BN + softplus epilogue; pixel = mt*16 + q*4 + r, cout = c
    const float scale = gamma[c] * (1.f / sqrtf(1.f + 1e-5f));
    const float bet = beta[c];
    #pragma unroll
    for (int mt = 0; mt < 4; ++mt) {
        const size_t ob = nb + (size_t)c * 64 + mt * 16 + q * 4;
        const float4 av = *(const float4*)&atom[ob];
        float av4[4] = {av.x, av.y, av.z, av.w};
        float4 ov;
        float ov4[4];
        #pragma unroll
        for (int r = 0; r < 4; ++r) {
            float aa = av4[r];
            float m = macc[mt][r] * LN2;     // fold exp2-domain factor back, once
            ov4[r] = fsoftplus(aa + (aa + m) * scale + bet);
        }
        ov.x = ov4[0]; ov.y = ov4[1]; ov.z = ov4[2]; ov.w = ov4[3];
        *(float4*)&out[ob] = ov;
    }
}

extern "C" void kernel_launch(void* const* d_in, const int* in_sizes, int n_in,
                              void* d_out, int out_size, void* d_ws, size_t ws_size,
                              hipStream_t stream) {
    const float* atom   = (const float*)d_in[0];
    const int*   esrc   = (const int*)d_in[1];
    const int*   etgt   = (const int*)d_in[2];
    const float* edge_w = (const float*)d_in[3];
    const float* node_w = (const float*)d_in[4];
    const float* lin_w  = (const float*)d_in[5];
    const float* lin_b  = (const float*)d_in[6];
    const float* gamma  = (const float*)d_in[7];
    const float* beta   = (const float*)d_in[8];
    float* out = (float*)d_out;

    const int total = in_sizes[0];      // N*16*8*8
    const int N = total / 1024;         // 8000
    const int E = in_sizes[1];          // 48000

    char* wsb = (char*)d_ws;
    unsigned* zcp    = (unsigned*)wsb;                                // N*512 u32 (packed bf16x2)
    unsigned* ncp    = (unsigned*)(wsb + (size_t)total * 2);          // N*512 u32
    short* wfrag_lin = (short*)(wsb + (size_t)total * 4);             // 10240 (16B-aligned)
    short* wfrag_nod = wfrag_lin + 10240;                             // 9216 (10240 alloc)
    int*   counts    = (int*)(wfrag_nod + 10240);                     // N
    int*   bucket    = counts + N;                                    // N*CAP
    int*   nlist     = bucket + (size_t)N * CAP;                      // N

    const int nhist = (E + 255) / 256;
    const int nconv3 = (N + 3) / 4;     // K3: 256-thread blocks, 4 nodes/block
    const int nconv4 = (N + 1) / 2;     // K4: 128-thread blocks, 2 nodes/block

    hipMemsetAsync(counts, 0, (size_t)N * 4, stream);
    prep_scatter_kernel<<<nhist + 8, 256, 0, stream>>>(
        edge_w, node_w, lin_w, esrc, etgt, wfrag_lin, wfrag_nod,
        counts, bucket, E, nhist);
    conv_order_kernel<<<nconv3 + 1, 256, 0, stream>>>(
        atom, wfrag_nod, zcp, ncp, counts, nlist, N, nconv3);
    node_edge_kernel<<<nconv4, 128, 0, stream>>>(
        atom, zcp, ncp, counts, bucket, nlist, wfrag_lin, lin_b, gamma, beta, out, N);
}

// Round 12
// 166.651 us; speedup vs baseline: 1.0328x; 1.0328x over previous
//
#include <hip/hip_runtime.h>

typedef __attribute__((ext_vector_type(8))) short short8;    // 8 bf16 (MFMA A/B frag)
typedef __attribute__((ext_vector_type(4))) float floatx4;   // 16x16 MFMA C/D frag
typedef __attribute__((ext_vector_type(16))) float floatx16; // 32x32 MFMA C/D frag

// Per-wave LDS staging: 100 halo pixels x 12 dwords (bf16x2[8] = 16ch | pad).
// pitch 12 dwords = 48B = 3 x 16B slots: stride 3 coprime with 8 bank-groups.
// R12: K4 back to SINGLE buffer (R10 form, 60 us). Double-buffer (R11)
// regressed 60->70: VGPR 60->84, occupancy 34->28, and the zvp
// consume-then-reload spine stayed serial anyway. Three pipelining attempts
// (R5 chain, R11 dbuf) all lost to register pressure -- do not re-try
// source-level pipelining on K4.
#define PITCH 12
#define REGSZ 1200
#define CAP 64            // fixed bucket capacity per node (mean deg = 6)
#define LOG2E 1.44269504088896340736f
#define LN2   0.6931471805599453f

__device__ __forceinline__ float frcp(float x) { return __builtin_amdgcn_rcpf(x); }
__device__ __forceinline__ float fsoftplus(float x) {
    return fmaxf(x, 0.f) + __logf(1.f + __expf(-fabsf(x)));
}
__device__ __forceinline__ float felu(float x) { return x > 0.f ? x : __expf(x) - 1.f; }

// RNE fp32 pair -> packed bf16x2 (a0 in low half, a1 in high half)
__device__ __forceinline__ unsigned pack2_rne(float a0, float a1) {
    unsigned u0 = __float_as_uint(a0), u1 = __float_as_uint(a1);
    u0 += 0x7fff + ((u0 >> 16) & 1);
    u1 += 0x7fff + ((u1 >> 16) & 1);
    return __builtin_amdgcn_perm(u1, u0, 0x07060302);  // [u1.b3,u1.b2,u0.b3,u0.b2]
}
__device__ __forceinline__ unsigned short f2bf_rne(float x) {
    unsigned u = __float_as_uint(x);
    u += 0x7fff + ((u >> 16) & 1);
    return (unsigned short)(u >> 16);
}
__device__ __forceinline__ float bf2f(unsigned short h) {
    return __uint_as_float(((unsigned)h) << 16);
}
// unpack packed bf16x2 word -> two floats (low = even channel)
__device__ __forceinline__ float up_lo(unsigned u) { return __uint_as_float(u << 16); }
__device__ __forceinline__ float up_hi(unsigned u) { return __uint_as_float(u & 0xffff0000u); }

// ---------------------------------------------------------------------------
// K1: fused histogram+scatter (blocks 0..nhist-1) + prep (8 blocks).
// Scan-free: fixed-capacity buckets (CAP slots/node); one atomic pass yields
// degree (counts) + grouped targets (bucket_tgt). Prep parallelized over 8
// blocks. wfrag_lin (10240): 16x16x32 B-operand layout for K4 (log2e-scaled;
// K4 reads only the hi half); wfrag_node (9216): 32x32x16 A-operand layout
// for K3 (K3 reads only ver=0/hi; lo kept for possible revert).
// ---------------------------------------------------------------------------
__global__ __launch_bounds__(256) void prep_scatter_kernel(
    const float* __restrict__ edge_w, const float* __restrict__ node_w,
    const float* __restrict__ lin_w, const int* __restrict__ esrc,
    const int* __restrict__ etgt,
    short* __restrict__ wfrag_lin, short* __restrict__ wfrag_node,
    int* __restrict__ counts, int* __restrict__ bucket_tgt, int E, int nhist)
{
    const int t = threadIdx.x;
    if ((int)blockIdx.x < nhist) {
        int i = blockIdx.x * 256 + t;
        if (i < E) {
            int s = esrc[i];
            int pos = atomicAdd(&counts[s], 1);
            if (pos < CAP) bucket_tgt[s * CAP + pos] = etgt[i];
        }
        return;
    }
    const int pb = blockIdx.x - nhist;   // 0..7
    // lin fragments: 16x16x32 B-operand (ver x nt x s x lane x j), log2e-scaled
    for (int i = pb * 256 + t; i < 10240; i += 2048) {
        int idx = i;
        int j = idx & 7; idx >>= 3;
        int lane = idx & 63; idx >>= 6;
        int s = idx % 5; idx /= 5;
        int nt = idx & 1;
        int ver = idx >> 1;
        int q = lane >> 4;
        int tap = 2 * s + (q >> 1);
        int cin = (q & 1) * 8 + j;
        int cout = nt * 16 + (lane & 15);
        float v = (tap < 9) ? lin_w[cout * 144 + cin * 9 + tap] * LOG2E : 0.f;
        unsigned short hi = f2bf_rne(v);
        wfrag_lin[i] = (short)(ver ? f2bf_rne(v - bf2f(hi)) : hi);
    }
    // node fragments: 32x32x16 A-operand (ver x tap x lane x j)
    for (int i = pb * 256 + t; i < 9216; i += 2048) {
        int j = i & 7;
        int lane = (i >> 3) & 63;
        int rest = i >> 9;            // 0..17
        int tap = rest % 9;
        int ver = rest / 9;           // 0=hi, 1=lo
        int row = lane & 31;
        int cin = (lane >> 5) * 8 + j;
        const float* src = (row < 16) ? edge_w : node_w;
        float v = src[(row & 15) * 144 + cin * 9 + tap];
        unsigned short hi = f2bf_rne(v);
        wfrag_node[i] = (short)(ver ? f2bf_rne(v - bf2f(hi)) : hi);
    }
}

// ---------------------------------------------------------------------------
// K3: degree-descending node order (block 0 -- R11-proven: first block
// overlaps the convs instead of running as a serial tail, -8 us) +
// node convs via 32x32x16 MFMA (blocks 1..nconv, 4 nodes/block).
// W hi-only (R10): 18 MFMA/node. zc/nc output as packed bf16x2 (adjacent-
// channel pairs = adjacent acc regs; row m = (i&1)+4*(i>>1)+2q).
// Memory-bound (~65 MB traffic): R10's compute halving was time-neutral.
// launch_bounds(256,3): (x,4) caps at 64 arch VGPRs and SPILLS (R1).
// ---------------------------------------------------------------------------
__global__ __launch_bounds__(256, 3) void conv_order_kernel(
    const float* __restrict__ atom, const short* __restrict__ wfrag_node,
    unsigned* __restrict__ zcp, unsigned* __restrict__ ncp,
    const int* __restrict__ counts, int* __restrict__ nlist,
    int N, int nconv)
{
    __shared__ unsigned zbuf[4 * REGSZ];     // 19.2 KB (conv part only)
    __shared__ int bh[64], bo[64];           // order part
    const int t = threadIdx.x;
    const int b = blockIdx.x;

    if (b == 0) {
        // ----- order: counting sort of nodes by degree, DESCENDING -----
        if (t < 64) bh[t] = 0;
        __syncthreads();
        for (int n = t; n < N; n += 256) {
            int deg = min(counts[n], CAP);
            atomicAdd(&bh[min(deg, 63)], 1);
        }
        __syncthreads();
        if (t == 0) {
            int run = 0;
            for (int d = 63; d >= 0; --d) { bo[d] = run; run += bh[d]; }
        }
        __syncthreads();
        for (int n = t; n < N; n += 256) {
            int deg = min(counts[n], CAP);
            int pos = atomicAdd(&bo[min(deg, 63)], 1);
            nlist[pos] = n;
        }
        return;
    }

    // ----- conv: 1 wave = 1 node, no barriers -----
    const int lane = t & 63;
    const int wv = t >> 6;
    const int n = (b - 1) * 4 + wv;
    if (n >= N) return;
    unsigned* zb = &zbuf[wv * REGSZ];
    for (int i = lane; i < REGSZ; i += 64) zb[i] = 0u;

    const int q = lane >> 5;       // cin-half (A/B k-half), outch +4q in D
    const int pcol = lane & 31;    // D column = pixel within tile

    const short8* wf = (const short8*)wfrag_node;
    short8 W[9];                   // hi-only (ver=0)
    #pragma unroll
    for (int tap = 0; tap < 9; ++tap)
        W[tap] = wf[tap * 64 + lane];

    const size_t nb = (size_t)n * 1024;
    float a[16];
    #pragma unroll
    for (int k = 0; k < 16; ++k) a[k] = atom[nb + k * 64 + lane];
    unsigned h[8];
    #pragma unroll
    for (int d = 0; d < 8; ++d) h[d] = pack2_rne(a[2 * d], a[2 * d + 1]);
    const int sbase = (((lane >> 3) + 1) * 10 + (lane & 7) + 1) * PITCH;
    *(uint4*)&zb[sbase]     = make_uint4(h[0], h[1], h[2], h[3]);
    *(uint4*)&zb[sbase + 4] = make_uint4(h[4], h[5], h[6], h[7]);

    // read base for tile0 pixel (pcol); tile1 = +4 rows = +480 dwords.
    const int rbase = ((pcol >> 3) * 10 + (pcol & 7)) * PITCH + q * 4;
    const size_t nbp = (size_t)n * 512;      // packed bf16x2 node block

    #pragma unroll
    for (int t2 = 0; t2 < 2; ++t2) {
        floatx16 acc = {0.f, 0.f, 0.f, 0.f, 0.f, 0.f, 0.f, 0.f,
                        0.f, 0.f, 0.f, 0.f, 0.f, 0.f, 0.f, 0.f};
        #pragma unroll
        for (int ky = 0; ky < 3; ++ky)
            #pragma unroll
            for (int kx = 0; kx < 3; ++kx) {
                short8 B = *(const short8*)&zb[rbase + t2 * 480 + (ky * 10 + kx) * PITCH];
                acc = __builtin_amdgcn_mfma_f32_32x32x16_bf16(W[ky * 3 + kx], B, acc, 0, 0, 0);
            }
        const int p = t2 * 32 + pcol;
        // channel-pair rows: pair i covers ch (2m, 2m+1), m = (i&1)+4*(i>>1)+2q
        #pragma unroll
        for (int i = 0; i < 4; ++i) {
            int m = (i & 1) + 4 * (i >> 1) + 2 * q;
            zcp[nbp + (size_t)m * 64 + p] = pack2_rne(acc[2 * i], acc[2 * i + 1]);
            ncp[nbp + (size_t)m * 64 + p] = pack2_rne(acc[8 + 2 * i], acc[9 + 2 * i]);
        }
    }
}

// ---------------------------------------------------------------------------
// K4: node-major edge processing; 1 wave = 1 node (degree-sorted via nlist).
// R10-measured 60 us form (restored in R12). 16x16x32 8-chain MFMA
// (R4-proven), W hi-only (R9): 40 MFMA/edge, A_bf16 x W_bf16. Wave-uniform
// values (n, bucket targets) readfirstlane'd into SGPRs. zc/nc packed bf16x2
// (R8): 8 gather loads/edge. Epilogue exp2-domain (weights/bias pre-scaled
// by log2e, ln2 folded back per node).
// DO NOT pipeline this kernel at source level: R5 (32x32 chain) and R11
// (LDS dbuf) both regressed via register pressure / occupancy.
// launch_bounds(128,3): no spill ((x,4) caps at 64 arch VGPRs and spills).
// ---------------------------------------------------------------------------
__global__ __launch_bounds__(128, 3) void node_edge_kernel(
    const float* __restrict__ atom, const unsigned* __restrict__ zcp,
    const unsigned* __restrict__ ncp, const int* __restrict__ counts,
    const int* __restrict__ bucket_tgt, const int* __restrict__ nlist,
    const short* __restrict__ wfrag_lin, const float* __restrict__ lin_b,
    const float* __restrict__ gamma, const float* __restrict__ beta,
    float* __restrict__ out, int N)
{
    __shared__ unsigned zbuf[2 * REGSZ];     // 9.6 KB
    const int t = threadIdx.x;
    const int lane = t & 63;
    const int wv = t >> 6;
    const int ni = blockIdx.x * 2 + wv;
    if (ni >= N) return;
    const int n = __builtin_amdgcn_readfirstlane(nlist[ni]);
    const int c = lane & 15;
    const int q = lane >> 4;
    unsigned* zb = &zbuf[wv * REGSZ];
    for (int i = lane; i < REGSZ; i += 64) zb[i] = 0u;

    const short8* wf = (const short8*)wfrag_lin;
    short8 W[2][5];                          // hi-only: [nt][s]
    #pragma unroll
    for (int nt = 0; nt < 2; ++nt)
        #pragma unroll
        for (int s = 0; s < 5; ++s)
            W[nt][s] = wf[(nt * 5 + s) * 64 + lane];

    int aoff[5];
    #pragma unroll
    for (int s = 0; s < 5; ++s) {
        int tap = 2 * s + (q >> 1);
        int ky = tap / 3, kx = tap - 3 * ky;
        aoff[s] = (tap < 9) ? ((((c >> 3) + ky) * 10 + (c & 7) + kx) * PITCH + (q & 1) * 4) : 0;
    }

    const size_t nb = (size_t)n * 1024;
    const size_t nbp = (size_t)n * 512;
    // nv: unpack packed nc once per node
    float nv[16];
    #pragma unroll
    for (int j = 0; j < 8; ++j) {
        unsigned u = ncp[nbp + (size_t)j * 64 + lane];
        nv[2 * j]     = up_lo(u);
        nv[2 * j + 1] = up_hi(u);
    }
    const int sbase = (((lane >> 3) + 1) * 10 + (lane & 7) + 1) * PITCH;

    const int off = n * CAP;
    const int deg = min(__builtin_amdgcn_readfirstlane(counts[n]), CAP);

    // exp2-domain biases (weights already carry the log2e factor)
    const float bf = lin_b[c] * LOG2E;
    const float bc = lin_b[c + 16] * LOG2E;
    float macc[4][4] = {{0.f}};

    unsigned zvp[8];
    int tnext = 0;
    if (deg > 0) {
        const unsigned* zp = zcp + (size_t)__builtin_amdgcn_readfirstlane(bucket_tgt[off]) * 512;
        #pragma unroll
        for (int j = 0; j < 8; ++j) zvp[j] = zp[(size_t)j * 64 + lane];
        if (deg > 1) tnext = __builtin_amdgcn_readfirstlane(bucket_tgt[off + 1]);
    }

    for (int it = 0; it < deg; ++it) {
        float a[16];
        #pragma unroll
        for (int d = 0; d < 8; ++d) {
            float z0 = up_lo(zvp[d]), z1 = up_hi(zvp[d]);
            a[2 * d]     = felu(nv[2 * d] * z0);
            a[2 * d + 1] = felu(nv[2 * d + 1] * z1);
        }

        if (it + 1 < deg) {                  // prefetch next edge ASAP (zvp consumed)
            const unsigned* zp = zcp + (size_t)tnext * 512;
            #pragma unroll
            for (int j = 0; j < 8; ++j) zvp[j] = zp[(size_t)j * 64 + lane];
            if (it + 2 < deg) tnext = __builtin_amdgcn_readfirstlane(bucket_tgt[off + it + 2]);
        }

        unsigned h[8];
        #pragma unroll
        for (int d = 0; d < 8; ++d) h[d] = pack2_rne(a[2 * d], a[2 * d + 1]);
        *(uint4*)&zb[sbase]     = make_uint4(h[0], h[1], h[2], h[3]);
        *(uint4*)&zb[sbase + 4] = make_uint4(h[4], h[5], h[6], h[7]);

        #pragma unroll
        for (int mt = 0; mt < 4; ++mt) {
            floatx4 a0 = {bf, bf, bf, bf}, a1 = {bc, bc, bc, bc};  // bias in C-init
            const int mb = mt * 2 * 10 * PITCH;
            #pragma unroll
            for (int s = 0; s < 5; ++s) {
                short8 Ah = *(const short8*)&zb[mb + aoff[s]];
                a0 = __builtin_amdgcn_mfma_f32_16x16x32_bf16(Ah, W[0][s], a0, 0, 0, 0);
                a1 = __builtin_amdgcn_mfma_f32_16x16x32_bf16(Ah, W[1][s], a1, 0, 0, 0);
            }
            // sigmoid(x)*softplus(y) in exp2 domain:
            //   a0 = x*log2e, a1 = y*log2e (biases included)
            //   sig = rcp(1 + 2^-a0); sp/ln2 = max(a1,0) + log2(1 + 2^-|a1|)
            #pragma unroll
            for (int r = 0; r < 4; ++r) {
                float sg = frcp(1.f + __builtin_amdgcn_exp2f(-a0[r]));
                float e1 = __builtin_amdgcn_exp2f(-fabsf(a1[r]));
                float u = fmaxf(a1[r], 0.f) + __builtin_amdgcn_logf(1.f + e1);
                macc[mt][r] = __builtin_fmaf(sg, u, macc[mt][r]);
            }
        }
    }

    // fused BN + softplus epilogue; pixel = mt*16 + q*4 + r, cout = c
    const float scale = gamma[c] * (1.f / sqrtf(1.f + 1e-5f));
    const float bet = beta[c];
    #pragma unroll
    for (int mt = 0; mt < 4; ++mt) {
        const size_t ob = nb + (size_t)c * 64 + mt * 16 + q * 4;
        const float4 av = *(const float4*)&atom[ob];
        float av4[4] = {av.x, av.y, av.z, av.w};
        float4 ov;
        float ov4[4];
        #pragma unroll
        for (int r = 0; r < 4; ++r) {
            float aa = av4[r];
            float m = macc[mt][r] * LN2;     // fold exp2-domain factor back, once
            ov4[r] = fsoftplus(aa + (aa + m) * scale + bet);
        }
        ov.x = ov4[0]; ov.y = ov4[1]; ov.z = ov4[2]; ov.w = ov4[3];
        *(float4*)&out[ob] = ov;
    }
}

extern "C" void kernel_launch(void* const* d_in, const int* in_sizes, int n_in,
                              void* d_out, int out_size, void* d_ws, size_t ws_size,
                              hipStream_t stream) {
    const float* atom   = (const float*)d_in[0];
    const int*   esrc   = (const int*)d_in[1];
    const int*   etgt   = (const int*)d_in[2];
    const float* edge_w = (const float*)d_in[3];
    const float* node_w = (const float*)d_in[4];
    const float* lin_w  = (const float*)d_in[5];
    const float* lin_b  = (const float*)d_in[6];
    const float* gamma  = (const float*)d_in[7];
    const float* beta   = (const float*)d_in[8];
    float* out = (float*)d_out;

    const int total = in_sizes[0];      // N*16*8*8
    const int N = total / 1024;         // 8000
    const int E = in_sizes[1];          // 48000

    char* wsb = (char*)d_ws;
    unsigned* zcp    = (unsigned*)wsb;                                // N*512 u32 (packed bf16x2)
    unsigned* ncp    = (unsigned*)(wsb + (size_t)total * 2);          // N*512 u32
    short* wfrag_lin = (short*)(wsb + (size_t)total * 4);             // 10240 (16B-aligned)
    short* wfrag_nod = wfrag_lin + 10240;                             // 9216 (10240 alloc)
    int*   counts    = (int*)(wfrag_nod + 10240);                     // N
    int*   bucket    = counts + N;                                    // N*CAP
    int*   nlist     = bucket + (size_t)N * CAP;                      // N

    const int nhist = (E + 255) / 256;
    const int nconv3 = (N + 3) / 4;     // K3: 256-thread blocks, 4 nodes/block
    const int nconv4 = (N + 1) / 2;     // K4: 128-thread blocks, 2 nodes/block

    hipMemsetAsync(counts, 0, (size_t)N * 4, stream);
    prep_scatter_kernel<<<nhist + 8, 256, 0, stream>>>(
        edge_w, node_w, lin_w, esrc, etgt, wfrag_lin, wfrag_nod,
        counts, bucket, E, nhist);
    conv_order_kernel<<<nconv3 + 1, 256, 0, stream>>>(
        atom, wfrag_nod, zcp, ncp, counts, nlist, N, nconv3);
    node_edge_kernel<<<nconv4, 128, 0, stream>>>(
        atom, zcp, ncp, counts, bucket, nlist, wfrag_lin, lin_b, gamma, beta, out, N);
}